// Round 1
// baseline (2211.135 us; speedup 1.0000x reference)
//
#include <hip/hip_runtime.h>
#include <hip/hip_bf16.h>
#include <stdint.h>

#define B_   32
#define K_   64
#define E_   512
#define H_   512
#define M_   512
#define T_   20
#define V_   32000
#define KIN  2048   // 2H + E + M

typedef __bf16 bf16x8 __attribute__((ext_vector_type(8)));
typedef float  f32x4  __attribute__((ext_vector_type(4)));

__device__ inline unsigned short f2bf_rne(float f) {
  union { float f; unsigned u; } v; v.f = f;
  unsigned r = v.u + 0x7FFFu + ((v.u >> 16) & 1u);
  return (unsigned short)(r >> 16);
}
__device__ inline float sigm(float x) { return 1.f / (1.f + expf(-x)); }
__device__ inline unsigned ordf(float f) {
  unsigned u = __float_as_uint(f);
  return (u & 0x80000000u) ? ~u : (u | 0x80000000u);
}

// ---- once per call: Wl fp32 -> bf16 -------------------------------------
__global__ void k_conv(const float* __restrict__ src, unsigned short* __restrict__ dst, int n4) {
  int i = blockIdx.x * blockDim.x + threadIdx.x;
  int stride = gridDim.x * blockDim.x;
  for (; i < n4; i += stride) {
    float4 v = ((const float4*)src)[i];
    ushort4 o;
    o.x = f2bf_rne(v.x); o.y = f2bf_rne(v.y); o.z = f2bf_rne(v.z); o.w = f2bf_rne(v.w);
    ((ushort4*)dst)[i] = o;
  }
}

// ---- once: h0=c0=enc[:,-1,:], enc_score[b][k]=dot(enc[b,k],Wa[1024:]) ----
__global__ void k_init(const float* __restrict__ enc, const float* __restrict__ Wa,
                       float* __restrict__ h0, float* __restrict__ c0,
                       float* __restrict__ enc_score) {
  int idx = blockIdx.x * 256 + threadIdx.x;        // 64 blocks * 256 = 16384
  int b = idx >> 9, i = idx & 511;
  float v = enc[(size_t)b * K_ * E_ + (size_t)(K_ - 1) * E_ + i];
  h0[b * H_ + i] = v;
  c0[b * H_ + i] = v;
  if (idx < B_ * K_) {
    int bb = idx >> 6, k = idx & 63;
    const float4* e4  = (const float4*)(enc + ((size_t)bb * K_ + k) * E_);
    const float4* wa4 = (const float4*)(Wa + 2 * H_);
    float acc = 0.f;
    #pragma unroll 4
    for (int q = 0; q < E_ / 4; ++q) {
      float4 a = e4[q], w = wa4[q];
      acc += a.x * w.x + a.y * w.y + a.z * w.z + a.w * w.w;
    }
    enc_score[idx] = acc;
  }
}

// ---- per step: attention + context + emb gather + final_input assembly ---
__global__ void k_attn(const float* __restrict__ enc, const float* __restrict__ embt,
                       const float* __restrict__ Wa, const float* __restrict__ ba,
                       const int* __restrict__ captions, const int* __restrict__ tf_flag,
                       const float* __restrict__ h_cur, const float* __restrict__ c_cur,
                       const float* __restrict__ enc_score,
                       unsigned long long* __restrict__ argkey,
                       float* __restrict__ x, unsigned short* __restrict__ finalb, int t) {
  int b = blockIdx.x;
  int tid = threadIdx.x;
  __shared__ float sred[4];
  __shared__ float attn_s[K_];
  __shared__ int   token_s;

  if (tid == 0) {
    int tok;
    if (tf_flag[0]) tok = captions[b * T_ + (t > 0 ? t - 1 : 0)];
    else if (t == 0) tok = captions[b * T_];
    else tok = (int)(0xFFFFFFFFu - (unsigned)(argkey[b] & 0xFFFFFFFFull));
    token_s = tok;
    argkey[b] = 0ull;   // reset for this step's k_logits
  }

  // state_score = dot([h,c], Wa[0:1024])
  float p = h_cur[b * H_ + tid]       * Wa[tid]
          + h_cur[b * H_ + tid + 256] * Wa[tid + 256]
          + c_cur[b * H_ + tid]       * Wa[512 + tid]
          + c_cur[b * H_ + tid + 256] * Wa[512 + tid + 256];
  for (int o = 32; o; o >>= 1) p += __shfl_down(p, o);
  if ((tid & 63) == 0) sred[tid >> 6] = p;
  __syncthreads();

  if (tid < K_) {
    float ss = sred[0] + sred[1] + sred[2] + sred[3] + ba[0];
    float s = tanhf(ss + enc_score[b * K_ + tid]);
    float m = s;
    for (int o = 32; o; o >>= 1) m = fmaxf(m, __shfl_xor(m, o));
    float e = expf(s - m);
    float sum = e;
    for (int o = 32; o; o >>= 1) sum += __shfl_xor(sum, o);
    attn_s[tid] = e / sum;
  }
  __syncthreads();

  const float* encb = enc + (size_t)b * K_ * E_;
  for (int e = tid; e < E_; e += 256) {
    float acc = 0.f;
    #pragma unroll 8
    for (int k = 0; k < K_; ++k) acc += attn_s[k] * encb[(size_t)k * E_ + e];
    x[b * (E_ + M_) + e] = acc;
    finalb[b * KIN + 2 * H_ + e] = f2bf_rne(acc);
  }
  int tok = token_s;
  for (int m = tid; m < M_; m += 256) {
    float em = embt[(size_t)tok * M_ + m];
    x[b * (E_ + M_) + E_ + m] = em;
    finalb[b * KIN + 2 * H_ + E_ + m] = f2bf_rne(em);
  }
  for (int i = tid; i < H_; i += 256) {
    finalb[b * KIN + i]      = f2bf_rne(h_cur[b * H_ + i]);
    finalb[b * KIN + H_ + i] = f2bf_rne(c_cur[b * H_ + i]);
  }
}

// ---- per step: logits = final_input @ Wl^T + bl  (MFMA bf16) -------------
template <bool WBF16>
__global__ __launch_bounds__(256) void k_logits(
    const unsigned short* __restrict__ wl_bf, const float* __restrict__ Wl,
    const unsigned short* __restrict__ finalb, const float* __restrict__ bl,
    const int* __restrict__ tf_flag, unsigned long long* __restrict__ argkey,
    float* __restrict__ out, int t) {
  int tid = threadIdx.x;
  int l  = tid & 63;
  int w  = tid >> 6;
  int v0 = blockIdx.x * 64 + w * 16;
  int lv = l & 15;
  int lg = l >> 4;
  int v  = v0 + lv;

  f32x4 acc0 = {0.f, 0.f, 0.f, 0.f};
  f32x4 acc1 = {0.f, 0.f, 0.f, 0.f};
  const unsigned short* arow0 = finalb + lv * KIN + lg * 8;
  const unsigned short* arow1 = finalb + (16 + lv) * KIN + lg * 8;

  #pragma unroll 4
  for (int kk = 0; kk < KIN / 32; ++kk) {
    int kb = kk * 32;
    bf16x8 a0 = *(const bf16x8*)(arow0 + kb);
    bf16x8 a1 = *(const bf16x8*)(arow1 + kb);
    bf16x8 bfr;
    if (WBF16) {
      bfr = *(const bf16x8*)(wl_bf + (size_t)v * KIN + kb + lg * 8);
    } else {
      const float* wr = Wl + (size_t)v * KIN + kb + lg * 8;
      float4 w0 = *(const float4*)(wr);
      float4 w1 = *(const float4*)(wr + 4);
      union { bf16x8 bv; unsigned short s[8]; } u;
      u.s[0] = f2bf_rne(w0.x); u.s[1] = f2bf_rne(w0.y);
      u.s[2] = f2bf_rne(w0.z); u.s[3] = f2bf_rne(w0.w);
      u.s[4] = f2bf_rne(w1.x); u.s[5] = f2bf_rne(w1.y);
      u.s[6] = f2bf_rne(w1.z); u.s[7] = f2bf_rne(w1.w);
      bfr = u.bv;
    }
    acc0 = __builtin_amdgcn_mfma_f32_16x16x32_bf16(a0, bfr, acc0, 0, 0, 0);
    acc1 = __builtin_amdgcn_mfma_f32_16x16x32_bf16(a1, bfr, acc1, 0, 0, 0);
  }

  float blv = bl[v];
  int r0 = lg * 4;
  bool do_arg = (tf_flag[0] == 0);
  #pragma unroll
  for (int j = 0; j < 4; ++j) {
    float x0 = acc0[j] + blv;
    float x1 = acc1[j] + blv;
    out[(size_t)(r0 + j) * (T_ * V_) + (size_t)t * V_ + v] = x0;
    out[(size_t)(16 + r0 + j) * (T_ * V_) + (size_t)t * V_ + v] = x1;
    if (do_arg) {  // only when teacher forcing is off
      unsigned long long k0 = ((unsigned long long)ordf(x0) << 32) | (0xFFFFFFFFu - (unsigned)v);
      unsigned long long k1 = ((unsigned long long)ordf(x1) << 32) | (0xFFFFFFFFu - (unsigned)v);
      atomicMax(&argkey[r0 + j], k0);
      atomicMax(&argkey[16 + r0 + j], k1);
    }
  }
}

// ---- per step: LSTM gates + state update (fp32) --------------------------
__global__ void k_lstm(const float* __restrict__ x, const float* __restrict__ W_ih,
                       const float* __restrict__ W_hh, const float* __restrict__ b_ih,
                       const float* __restrict__ b_hh, const float* __restrict__ h_cur,
                       const float* __restrict__ c_cur, float* __restrict__ h_nxt,
                       float* __restrict__ c_nxt) {
  int b  = blockIdx.x >> 3;
  int ic = blockIdx.x & 7;
  int tid = threadIdx.x;
  __shared__ float xs[E_ + M_];
  __shared__ float hs[H_];
  __shared__ float gs[256];
  for (int i = tid; i < E_ + M_; i += 256) xs[i] = x[b * (E_ + M_) + i];
  for (int i = tid; i < H_; i += 256)      hs[i] = h_cur[b * H_ + i];
  __syncthreads();

  int g = tid >> 6, il = tid & 63;
  int i = ic * 64 + il;
  int j = g * H_ + i;
  const float4* wi = (const float4*)(W_ih + (size_t)j * (E_ + M_));
  const float4* wh = (const float4*)(W_hh + (size_t)j * H_);
  float acc = 0.f;
  #pragma unroll 4
  for (int q = 0; q < (E_ + M_) / 4; ++q) {
    float4 wv = wi[q];
    acc += wv.x * xs[4 * q] + wv.y * xs[4 * q + 1] + wv.z * xs[4 * q + 2] + wv.w * xs[4 * q + 3];
  }
  #pragma unroll 4
  for (int q = 0; q < H_ / 4; ++q) {
    float4 wv = wh[q];
    acc += wv.x * hs[4 * q] + wv.y * hs[4 * q + 1] + wv.z * hs[4 * q + 2] + wv.w * hs[4 * q + 3];
  }
  acc += b_ih[j] + b_hh[j];
  gs[tid] = acc;
  __syncthreads();

  if (tid < 64) {
    int ii = ic * 64 + tid;
    float ig = gs[tid], fg = gs[64 + tid], gg = gs[128 + tid], og = gs[192 + tid];
    float cv = c_cur[b * H_ + ii];
    float cn = sigm(fg) * cv + sigm(ig) * tanhf(gg);
    float hn = sigm(og) * tanhf(cn);
    c_nxt[b * H_ + ii] = cn;
    h_nxt[b * H_ + ii] = hn;
  }
}

// ---- final: in-place log_softmax over each (b,t) row ---------------------
__global__ void k_lsm(float* __restrict__ out) {
  float4* p = (float4*)(out + (size_t)blockIdx.x * V_);
  int tid = threadIdx.x;
  __shared__ float sr[4];
  const int N4 = V_ / 4;  // 8000
  float m = -1e30f;
  for (int i = tid; i < N4; i += 256) {
    float4 v = p[i];
    m = fmaxf(fmaxf(fmaxf(m, v.x), fmaxf(v.y, v.z)), v.w);
  }
  for (int o = 32; o; o >>= 1) m = fmaxf(m, __shfl_xor(m, o));
  if ((tid & 63) == 0) sr[tid >> 6] = m;
  __syncthreads();
  m = fmaxf(fmaxf(sr[0], sr[1]), fmaxf(sr[2], sr[3]));
  __syncthreads();
  float s = 0.f;
  for (int i = tid; i < N4; i += 256) {
    float4 v = p[i];
    s += expf(v.x - m) + expf(v.y - m) + expf(v.z - m) + expf(v.w - m);
  }
  for (int o = 32; o; o >>= 1) s += __shfl_xor(s, o);
  if ((tid & 63) == 0) sr[tid >> 6] = s;
  __syncthreads();
  s = sr[0] + sr[1] + sr[2] + sr[3];
  float lse = m + logf(s);
  for (int i = tid; i < N4; i += 256) {
    float4 v = p[i];
    v.x -= lse; v.y -= lse; v.z -= lse; v.w -= lse;
    p[i] = v;
  }
}

extern "C" void kernel_launch(void* const* d_in, const int* in_sizes, int n_in,
                              void* d_out, int out_size, void* d_ws, size_t ws_size,
                              hipStream_t stream) {
  const float* enc      = (const float*)d_in[0];
  const float* embt     = (const float*)d_in[1];
  const float* Wa       = (const float*)d_in[2];
  const float* ba       = (const float*)d_in[3];
  const float* W_ih     = (const float*)d_in[4];
  const float* W_hh     = (const float*)d_in[5];
  const float* b_ih     = (const float*)d_in[6];
  const float* b_hh     = (const float*)d_in[7];
  const float* Wl       = (const float*)d_in[8];
  const float* bl       = (const float*)d_in[9];
  const int*   captions = (const int*)d_in[10];
  const int*   tf       = (const int*)d_in[11];
  float* out = (float*)d_out;
  char*  ws  = (char*)d_ws;

  // workspace layout (small buffers first so fp32-fallback works with tiny ws)
  size_t off = 0;
  unsigned short* finalb = (unsigned short*)(ws + off); off += (size_t)B_ * KIN * 2;        // 131072
  float* xbuf            = (float*)(ws + off);          off += (size_t)B_ * (E_ + M_) * 4;  // 131072
  float* hb              = (float*)(ws + off);          off += (size_t)2 * B_ * H_ * 4;     // 131072
  float* cb              = (float*)(ws + off);          off += (size_t)2 * B_ * H_ * 4;     // 131072
  float* enc_score       = (float*)(ws + off);          off += (size_t)B_ * K_ * 4;         // 8192
  unsigned long long* argkey = (unsigned long long*)(ws + off); off += 256;
  off = (off + 1023) & ~(size_t)1023;
  unsigned short* wl_bf  = (unsigned short*)(ws + off);
  size_t need = off + (size_t)V_ * KIN * 2;
  bool wl16 = (ws_size >= need);

  float* hbuf[2] = { hb, hb + B_ * H_ };
  float* cbuf[2] = { cb, cb + B_ * H_ };

  k_init<<<64, 256, 0, stream>>>(enc, Wa, hbuf[0], cbuf[0], enc_score);
  if (wl16)
    k_conv<<<8192, 256, 0, stream>>>(Wl, wl_bf, V_ * KIN / 4);

  for (int t = 0; t < T_; ++t) {
    int cur = t & 1, nxt = cur ^ 1;
    k_attn<<<B_, 256, 0, stream>>>(enc, embt, Wa, ba, captions, tf,
                                   hbuf[cur], cbuf[cur], enc_score, argkey,
                                   xbuf, finalb, t);
    if (wl16)
      k_logits<true><<<V_ / 64, 256, 0, stream>>>(wl_bf, Wl, finalb, bl, tf, argkey, out, t);
    else
      k_logits<false><<<V_ / 64, 256, 0, stream>>>(wl_bf, Wl, finalb, bl, tf, argkey, out, t);
    k_lstm<<<B_ * 8, 256, 0, stream>>>(xbuf, W_ih, W_hh, b_ih, b_hh,
                                       hbuf[cur], cbuf[cur], hbuf[nxt], cbuf[nxt]);
  }
  k_lsm<<<B_ * T_, 256, 0, stream>>>(out);
}

// Round 2
// 1749.096 us; speedup vs baseline: 1.2642x; 1.2642x over previous
//
#include <hip/hip_runtime.h>
#include <hip/hip_bf16.h>
#include <stdint.h>

#define B_   32
#define K_   64
#define E_   512
#define H_   512
#define M_   512
#define T_   20
#define V_   32000
#define KIN  2048   // 2H + E + M
#define KL   1536   // E + M + H (lstm concat K)

typedef __bf16 bf16x8 __attribute__((ext_vector_type(8)));
typedef float  f32x4  __attribute__((ext_vector_type(4)));

__device__ inline unsigned short f2bf_rne(float f) {
  union { float f; unsigned u; } v; v.f = f;
  unsigned r = v.u + 0x7FFFu + ((v.u >> 16) & 1u);
  return (unsigned short)(r >> 16);
}
__device__ inline float bf2f(unsigned short s) {
  union { unsigned u; float f; } v; v.u = ((unsigned)s) << 16;
  return v.f;
}
__device__ inline float sigm(float x) { return 1.f / (1.f + expf(-x)); }
__device__ inline unsigned ordf(float f) {
  unsigned u = __float_as_uint(f);
  return (u & 0x80000000u) ? ~u : (u | 0x80000000u);
}

// ---- once: Wl fp32 -> bf16 ----------------------------------------------
__global__ void k_conv(const float* __restrict__ src, unsigned short* __restrict__ dst, int n4) {
  int i = blockIdx.x * blockDim.x + threadIdx.x;
  int stride = gridDim.x * blockDim.x;
  for (; i < n4; i += stride) {
    float4 v = ((const float4*)src)[i];
    ushort4 o;
    o.x = f2bf_rne(v.x); o.y = f2bf_rne(v.y); o.z = f2bf_rne(v.z); o.w = f2bf_rne(v.w);
    ((ushort4*)dst)[i] = o;
  }
}

// ---- once: [W_ih | W_hh] -> bf16 hi/lo split ([2048][1536]) --------------
__global__ void k_convW(const float* __restrict__ W_ih, const float* __restrict__ W_hh,
                        unsigned short* __restrict__ whi, unsigned short* __restrict__ wlo) {
  int idx4 = blockIdx.x * 256 + threadIdx.x;       // 3072 blocks: 2048*1536/4
  int j  = idx4 / (KL / 4);
  int k0 = (idx4 % (KL / 4)) * 4;
  float4 w;
  if (k0 < E_ + M_) w = *(const float4*)(W_ih + (size_t)j * (E_ + M_) + k0);
  else              w = *(const float4*)(W_hh + (size_t)j * H_ + (k0 - (E_ + M_)));
  ushort4 hi, lo;
  float f[4] = {w.x, w.y, w.z, w.w};
  unsigned short hs[4], ls[4];
  #pragma unroll
  for (int q = 0; q < 4; ++q) {
    hs[q] = f2bf_rne(f[q]);
    ls[q] = f2bf_rne(f[q] - bf2f(hs[q]));
  }
  hi.x = hs[0]; hi.y = hs[1]; hi.z = hs[2]; hi.w = hs[3];
  lo.x = ls[0]; lo.y = ls[1]; lo.z = ls[2]; lo.w = ls[3];
  *(ushort4*)(whi + (size_t)j * KL + k0) = hi;
  *(ushort4*)(wlo + (size_t)j * KL + k0) = lo;
}

// ---- once: h0=c0=enc[:,-1,:] (fp32 + bf16 into finalb[0]), enc_score ----
__global__ void k_init(const float* __restrict__ enc, const float* __restrict__ Wa,
                       float* __restrict__ h0, float* __restrict__ c0,
                       unsigned short* __restrict__ finalb0,
                       float* __restrict__ enc_score) {
  int idx = blockIdx.x * 256 + threadIdx.x;        // 64 blocks * 256 = 16384
  int b = idx >> 9, i = idx & 511;
  float v = enc[(size_t)b * K_ * E_ + (size_t)(K_ - 1) * E_ + i];
  h0[b * H_ + i] = v;
  c0[b * H_ + i] = v;
  unsigned short bv = f2bf_rne(v);
  finalb0[b * KIN + i] = bv;          // h rows
  finalb0[b * KIN + H_ + i] = bv;     // c rows
  if (idx < B_ * K_) {
    int bb = idx >> 6, k = idx & 63;
    const float4* e4  = (const float4*)(enc + ((size_t)bb * K_ + k) * E_);
    const float4* wa4 = (const float4*)(Wa + 2 * H_);
    float acc = 0.f;
    #pragma unroll 4
    for (int q = 0; q < E_ / 4; ++q) {
      float4 a = e4[q], w = wa4[q];
      acc += a.x * w.x + a.y * w.y + a.z * w.z + a.w * w.w;
    }
    enc_score[idx] = acc;
  }
}

// ---- per step: attention + context + emb -> finalb[cur][1024:2048] -------
__global__ void k_attn(const float* __restrict__ enc, const float* __restrict__ embt,
                       const float* __restrict__ Wa, const float* __restrict__ ba,
                       const int* __restrict__ captions, const int* __restrict__ tf_flag,
                       const float* __restrict__ h_cur, const float* __restrict__ c_cur,
                       const float* __restrict__ enc_score,
                       unsigned long long* __restrict__ argkey,
                       unsigned short* __restrict__ finalb, int t) {
  int b = blockIdx.x;
  int tid = threadIdx.x;
  __shared__ float sred[4];
  __shared__ float attn_s[K_];
  __shared__ int   token_s;

  if (tid == 0) {
    int tok;
    if (tf_flag[0]) tok = captions[b * T_ + (t > 0 ? t - 1 : 0)];
    else if (t == 0) tok = captions[b * T_];
    else tok = (int)(0xFFFFFFFFu - (unsigned)(argkey[b] & 0xFFFFFFFFull));
    token_s = tok;
    argkey[b] = 0ull;   // reset for this step's k_logits
  }

  float p = h_cur[b * H_ + tid]       * Wa[tid]
          + h_cur[b * H_ + tid + 256] * Wa[tid + 256]
          + c_cur[b * H_ + tid]       * Wa[512 + tid]
          + c_cur[b * H_ + tid + 256] * Wa[512 + tid + 256];
  for (int o = 32; o; o >>= 1) p += __shfl_down(p, o);
  if ((tid & 63) == 0) sred[tid >> 6] = p;
  __syncthreads();

  if (tid < K_) {
    float ss = sred[0] + sred[1] + sred[2] + sred[3] + ba[0];
    float s = tanhf(ss + enc_score[b * K_ + tid]);
    float m = s;
    for (int o = 32; o; o >>= 1) m = fmaxf(m, __shfl_xor(m, o));
    float e = expf(s - m);
    float sum = e;
    for (int o = 32; o; o >>= 1) sum += __shfl_xor(sum, o);
    attn_s[tid] = e / sum;
  }
  __syncthreads();

  const float* encb = enc + (size_t)b * K_ * E_;
  for (int e = tid; e < E_; e += 256) {
    float acc = 0.f;
    #pragma unroll 8
    for (int k = 0; k < K_; ++k) acc += attn_s[k] * encb[(size_t)k * E_ + e];
    finalb[b * KIN + 2 * H_ + e] = f2bf_rne(acc);          // context
  }
  int tok = token_s;
  for (int m = tid; m < M_; m += 256) {
    finalb[b * KIN + 2 * H_ + E_ + m] = f2bf_rne(embt[(size_t)tok * M_ + m]);  // emb
  }
}

// ---- per step: logits = final_input @ Wl^T + bl  (MFMA bf16) -------------
__global__ __launch_bounds__(256) void k_logits(
    const unsigned short* __restrict__ wl_bf,
    const unsigned short* __restrict__ finalb, const float* __restrict__ bl,
    const int* __restrict__ tf_flag, unsigned long long* __restrict__ argkey,
    float* __restrict__ out, int t) {
  int tid = threadIdx.x;
  int l  = tid & 63;
  int w  = tid >> 6;
  int v0 = blockIdx.x * 64 + w * 16;
  int lv = l & 15;
  int lg = l >> 4;
  int v  = v0 + lv;

  f32x4 acc0 = {0.f, 0.f, 0.f, 0.f};
  f32x4 acc1 = {0.f, 0.f, 0.f, 0.f};
  const unsigned short* arow0 = finalb + lv * KIN + lg * 8;
  const unsigned short* arow1 = finalb + (16 + lv) * KIN + lg * 8;
  const unsigned short* brow  = wl_bf + (size_t)v * KIN + lg * 8;

  #pragma unroll 8
  for (int kk = 0; kk < KIN / 32; ++kk) {
    int kb = kk * 32;
    bf16x8 a0 = *(const bf16x8*)(arow0 + kb);
    bf16x8 a1 = *(const bf16x8*)(arow1 + kb);
    bf16x8 bfr = *(const bf16x8*)(brow + kb);
    acc0 = __builtin_amdgcn_mfma_f32_16x16x32_bf16(a0, bfr, acc0, 0, 0, 0);
    acc1 = __builtin_amdgcn_mfma_f32_16x16x32_bf16(a1, bfr, acc1, 0, 0, 0);
  }

  float blv = bl[v];
  int r0 = lg * 4;
  bool do_arg = (tf_flag[0] == 0);
  #pragma unroll
  for (int j = 0; j < 4; ++j) {
    float x0 = acc0[j] + blv;
    float x1 = acc1[j] + blv;
    out[(size_t)(r0 + j) * (T_ * V_) + (size_t)t * V_ + v] = x0;
    out[(size_t)(16 + r0 + j) * (T_ * V_) + (size_t)t * V_ + v] = x1;
    if (do_arg) {
      unsigned long long k0 = ((unsigned long long)ordf(x0) << 32) | (0xFFFFFFFFu - (unsigned)v);
      unsigned long long k1 = ((unsigned long long)ordf(x1) << 32) | (0xFFFFFFFFu - (unsigned)v);
      atomicMax(&argkey[r0 + j], k0);
      atomicMax(&argkey[16 + r0 + j], k1);
    }
  }
}

// ---- per step: LSTM via MFMA (weights read once), fused gate update ------
// grid: 32 blocks, block handles ii in [bid*16, bid*16+16). wave g = gate g.
// A = wcat hi/lo rows j = g*512 + ii0 + m (16 rows). B = finalb[cur] remapped:
// k in [0,1024)   -> finalb offset 1024+k  (x = [context, emb])
// k in [1024,1536)-> finalb offset k-1024  (h)
__global__ __launch_bounds__(256) void k_lstm(
    const unsigned short* __restrict__ whi, const unsigned short* __restrict__ wlo,
    const unsigned short* __restrict__ finalb_cur,
    const float* __restrict__ b_ih, const float* __restrict__ b_hh,
    const float* __restrict__ c_cur,
    float* __restrict__ h_nxt, float* __restrict__ c_nxt,
    unsigned short* __restrict__ finalb_nxt) {
  int tid = threadIdx.x;
  int g   = tid >> 6;          // wave = gate
  int l   = tid & 63;
  int lv  = l & 15;
  int lg  = l >> 4;
  int ii0 = blockIdx.x * 16;

  __shared__ float gs[4][16][32];

  int j = g * H_ + ii0 + lv;                       // gate row
  const unsigned short* ahi = whi + (size_t)j * KL + lg * 8;
  const unsigned short* alo = wlo + (size_t)j * KL + lg * 8;
  const unsigned short* b0r = finalb_cur + lv * KIN;          // b = lv
  const unsigned short* b1r = finalb_cur + (16 + lv) * KIN;   // b = 16+lv

  f32x4 acc0 = {0.f, 0.f, 0.f, 0.f};
  f32x4 acc1 = {0.f, 0.f, 0.f, 0.f};

  #pragma unroll 8
  for (int kk = 0; kk < KL / 32; ++kk) {
    int kb = kk * 32;
    int koff = kb + lg * 8;
    int boff = (kb < E_ + M_) ? (2 * H_ + koff) : (koff - (E_ + M_));
    bf16x8 a_hi = *(const bf16x8*)(ahi + kb);
    bf16x8 a_lo = *(const bf16x8*)(alo + kb);
    bf16x8 bb0  = *(const bf16x8*)(b0r + boff);
    bf16x8 bb1  = *(const bf16x8*)(b1r + boff);
    acc0 = __builtin_amdgcn_mfma_f32_16x16x32_bf16(a_hi, bb0, acc0, 0, 0, 0);
    acc0 = __builtin_amdgcn_mfma_f32_16x16x32_bf16(a_lo, bb0, acc0, 0, 0, 0);
    acc1 = __builtin_amdgcn_mfma_f32_16x16x32_bf16(a_hi, bb1, acc1, 0, 0, 0);
    acc1 = __builtin_amdgcn_mfma_f32_16x16x32_bf16(a_lo, bb1, acc1, 0, 0, 0);
  }

  // D: row m = 4*lg + reg (gate-row within the 16), col = lv (batch)
  #pragma unroll
  for (int jreg = 0; jreg < 4; ++jreg) {
    gs[g][4 * lg + jreg][lv]      = acc0[jreg];
    gs[g][4 * lg + jreg][16 + lv] = acc1[jreg];
  }
  __syncthreads();

  // 512 outputs: 16 ii * 32 b; two per thread
  #pragma unroll
  for (int r = 0; r < 2; ++r) {
    int idx = tid + r * 256;
    int b  = idx & 31;
    int ii = idx >> 5;
    int iglob = ii0 + ii;
    float ig = gs[0][ii][b] + b_ih[0 * H_ + iglob] + b_hh[0 * H_ + iglob];
    float fg = gs[1][ii][b] + b_ih[1 * H_ + iglob] + b_hh[1 * H_ + iglob];
    float gg = gs[2][ii][b] + b_ih[2 * H_ + iglob] + b_hh[2 * H_ + iglob];
    float og = gs[3][ii][b] + b_ih[3 * H_ + iglob] + b_hh[3 * H_ + iglob];
    float cv = c_cur[b * H_ + iglob];
    float cn = sigm(fg) * cv + sigm(ig) * tanhf(gg);
    float hn = sigm(og) * tanhf(cn);
    c_nxt[b * H_ + iglob] = cn;
    h_nxt[b * H_ + iglob] = hn;
    finalb_nxt[b * KIN + iglob]      = f2bf_rne(hn);
    finalb_nxt[b * KIN + H_ + iglob] = f2bf_rne(cn);
  }
}

// ---- final: in-place log_softmax, online max+sum (2 passes) --------------
__global__ void k_lsm(float* __restrict__ out) {
  float4* p = (float4*)(out + (size_t)blockIdx.x * V_);
  int tid = threadIdx.x;
  __shared__ float smax[4], ssum[4];
  const int N4 = V_ / 4;  // 8000
  float m = -1e30f, s = 0.f;
  for (int i = tid; i < N4; i += 256) {
    float4 v = p[i];
    float lm = fmaxf(fmaxf(v.x, v.y), fmaxf(v.z, v.w));
    if (lm > m) { s *= expf(m - lm); m = lm; }
    s += expf(v.x - m) + expf(v.y - m) + expf(v.z - m) + expf(v.w - m);
  }
  for (int o = 32; o; o >>= 1) {
    float m2 = __shfl_xor(m, o), s2 = __shfl_xor(s, o);
    float mn = fmaxf(m, m2);
    s = s * expf(m - mn) + s2 * expf(m2 - mn);
    m = mn;
  }
  if ((tid & 63) == 0) { smax[tid >> 6] = m; ssum[tid >> 6] = s; }
  __syncthreads();
  float mg = fmaxf(fmaxf(smax[0], smax[1]), fmaxf(smax[2], smax[3]));
  float sg = ssum[0] * expf(smax[0] - mg) + ssum[1] * expf(smax[1] - mg)
           + ssum[2] * expf(smax[2] - mg) + ssum[3] * expf(smax[3] - mg);
  float lse = mg + logf(sg);
  for (int i = tid; i < N4; i += 256) {
    float4 v = p[i];
    v.x -= lse; v.y -= lse; v.z -= lse; v.w -= lse;
    p[i] = v;
  }
}

extern "C" void kernel_launch(void* const* d_in, const int* in_sizes, int n_in,
                              void* d_out, int out_size, void* d_ws, size_t ws_size,
                              hipStream_t stream) {
  const float* enc      = (const float*)d_in[0];
  const float* embt     = (const float*)d_in[1];
  const float* Wa       = (const float*)d_in[2];
  const float* ba       = (const float*)d_in[3];
  const float* W_ih     = (const float*)d_in[4];
  const float* W_hh     = (const float*)d_in[5];
  const float* b_ih     = (const float*)d_in[6];
  const float* b_hh     = (const float*)d_in[7];
  const float* Wl       = (const float*)d_in[8];
  const float* bl       = (const float*)d_in[9];
  const int*   captions = (const int*)d_in[10];
  const int*   tf       = (const int*)d_in[11];
  float* out = (float*)d_out;
  char*  ws  = (char*)d_ws;

  size_t off = 0;
  unsigned short* finalb2 = (unsigned short*)(ws + off); off += (size_t)2 * B_ * KIN * 2;   // 256KB
  float* hb               = (float*)(ws + off);          off += (size_t)2 * B_ * H_ * 4;
  float* cb               = (float*)(ws + off);          off += (size_t)2 * B_ * H_ * 4;
  float* enc_score        = (float*)(ws + off);          off += (size_t)B_ * K_ * 4;
  unsigned long long* argkey = (unsigned long long*)(ws + off); off += 256;
  off = (off + 1023) & ~(size_t)1023;
  unsigned short* whi = (unsigned short*)(ws + off); off += (size_t)4 * H_ * KL * 2;        // 6.3MB
  unsigned short* wlo = (unsigned short*)(ws + off); off += (size_t)4 * H_ * KL * 2;        // 6.3MB
  unsigned short* wl_bf = (unsigned short*)(ws + off); off += (size_t)V_ * KIN * 2;         // 131MB

  unsigned short* finalb[2] = { finalb2, finalb2 + B_ * KIN };
  float* hbuf[2] = { hb, hb + B_ * H_ };
  float* cbuf[2] = { cb, cb + B_ * H_ };

  k_init<<<64, 256, 0, stream>>>(enc, Wa, hbuf[0], cbuf[0], finalb[0], enc_score);
  k_conv<<<8192, 256, 0, stream>>>(Wl, wl_bf, V_ * KIN / 4);
  k_convW<<<4 * H_ * KL / 1024, 256, 0, stream>>>(W_ih, W_hh, whi, wlo);

  for (int t = 0; t < T_; ++t) {
    int cur = t & 1, nxt = cur ^ 1;
    k_attn<<<B_, 256, 0, stream>>>(enc, embt, Wa, ba, captions, tf,
                                   hbuf[cur], cbuf[cur], enc_score, argkey,
                                   finalb[cur], t);
    k_logits<<<V_ / 64, 256, 0, stream>>>(wl_bf, finalb[cur], bl, tf, argkey, out, t);
    k_lstm<<<H_ / 16, 256, 0, stream>>>(whi, wlo, finalb[cur], b_ih, b_hh,
                                        cbuf[cur], hbuf[nxt], cbuf[nxt], finalb[nxt]);
  }
  k_lsm<<<B_ * T_, 256, 0, stream>>>(out);
}

// Round 4
// 1278.716 us; speedup vs baseline: 1.7292x; 1.3679x over previous
//
#include <hip/hip_runtime.h>
#include <hip/hip_bf16.h>
#include <stdint.h>

#define B_   32
#define K_   64
#define E_   512
#define H_   512
#define M_   512
#define T_   20
#define V_   32000
#define KIN  2048   // 2H + E + M
#define KL   1536   // E + M + H (lstm concat K)

typedef __bf16 bf16x8 __attribute__((ext_vector_type(8)));
typedef float  f32x4  __attribute__((ext_vector_type(4)));

__device__ inline unsigned short f2bf_rne(float f) {
  union { float f; unsigned u; } v; v.f = f;
  unsigned r = v.u + 0x7FFFu + ((v.u >> 16) & 1u);
  return (unsigned short)(r >> 16);
}
__device__ inline float bf2f(unsigned short s) {
  union { unsigned u; float f; } v; v.u = ((unsigned)s) << 16;
  return v.f;
}
__device__ inline float sigm(float x) { return 1.f / (1.f + expf(-x)); }
__device__ inline unsigned ordf(float f) {
  unsigned u = __float_as_uint(f);
  return (u & 0x80000000u) ? ~u : (u | 0x80000000u);
}

__device__ __forceinline__ void gload16(const void* g, void* l) {
  __builtin_amdgcn_global_load_lds(
      (const __attribute__((address_space(1))) void*)g,
      (__attribute__((address_space(3))) void*)l, 16, 0, 0);
}

// ---- once: Wl fp32 -> bf16 (NT loads: don't pollute L3 with fp32) --------
__global__ void k_conv(const float* __restrict__ src, unsigned short* __restrict__ dst, int n4) {
  int i = blockIdx.x * blockDim.x + threadIdx.x;
  int stride = gridDim.x * blockDim.x;
  for (; i < n4; i += stride) {
    f32x4 v = __builtin_nontemporal_load((const f32x4*)src + i);
    ushort4 o;
    o.x = f2bf_rne(v.x); o.y = f2bf_rne(v.y); o.z = f2bf_rne(v.z); o.w = f2bf_rne(v.w);
    ((ushort4*)dst)[i] = o;
  }
}

// ---- once: [W_ih | W_hh] -> bf16 hi/lo split ([2048][1536]) --------------
__global__ void k_convW(const float* __restrict__ W_ih, const float* __restrict__ W_hh,
                        unsigned short* __restrict__ whi, unsigned short* __restrict__ wlo) {
  int idx4 = blockIdx.x * 256 + threadIdx.x;
  int j  = idx4 / (KL / 4);
  int k0 = (idx4 % (KL / 4)) * 4;
  float4 w;
  if (k0 < E_ + M_) w = *(const float4*)(W_ih + (size_t)j * (E_ + M_) + k0);
  else              w = *(const float4*)(W_hh + (size_t)j * H_ + (k0 - (E_ + M_)));
  ushort4 hi, lo;
  float f[4] = {w.x, w.y, w.z, w.w};
  unsigned short hs[4], ls[4];
  #pragma unroll
  for (int q = 0; q < 4; ++q) {
    hs[q] = f2bf_rne(f[q]);
    ls[q] = f2bf_rne(f[q] - bf2f(hs[q]));
  }
  hi.x = hs[0]; hi.y = hs[1]; hi.z = hs[2]; hi.w = hs[3];
  lo.x = ls[0]; lo.y = ls[1]; lo.z = ls[2]; lo.w = ls[3];
  *(ushort4*)(whi + (size_t)j * KL + k0) = hi;
  *(ushort4*)(wlo + (size_t)j * KL + k0) = lo;
}

// ---- once: h0=c0=enc[:,-1,:] (fp32 + bf16 into finalb[0]), enc_score ----
__global__ void k_init(const float* __restrict__ enc, const float* __restrict__ Wa,
                       float* __restrict__ h0, float* __restrict__ c0,
                       unsigned short* __restrict__ finalb0,
                       float* __restrict__ enc_score) {
  int idx = blockIdx.x * 256 + threadIdx.x;
  int b = idx >> 9, i = idx & 511;
  float v = enc[(size_t)b * K_ * E_ + (size_t)(K_ - 1) * E_ + i];
  h0[b * H_ + i] = v;
  c0[b * H_ + i] = v;
  unsigned short bv = f2bf_rne(v);
  finalb0[b * KIN + i] = bv;
  finalb0[b * KIN + H_ + i] = bv;
  if (idx < B_ * K_) {
    int bb = idx >> 6, k = idx & 63;
    const float4* e4  = (const float4*)(enc + ((size_t)bb * K_ + k) * E_);
    const float4* wa4 = (const float4*)(Wa + 2 * H_);
    float acc = 0.f;
    #pragma unroll 4
    for (int q = 0; q < E_ / 4; ++q) {
      float4 a = e4[q], w = wa4[q];
      acc += a.x * w.x + a.y * w.y + a.z * w.z + a.w * w.w;
    }
    enc_score[idx] = acc;
  }
}

// ---- per step: attention + context + emb -> finalb[cur][1024:2048] -------
__global__ void k_attn(const float* __restrict__ enc, const float* __restrict__ embt,
                       const float* __restrict__ Wa, const float* __restrict__ ba,
                       const int* __restrict__ captions, const int* __restrict__ tf_flag,
                       const float* __restrict__ h_cur, const float* __restrict__ c_cur,
                       const float* __restrict__ enc_score,
                       unsigned long long* __restrict__ argkey,
                       unsigned short* __restrict__ finalb, int t) {
  int b = blockIdx.x;
  int tid = threadIdx.x;
  __shared__ float sred[4];
  __shared__ float attn_s[K_];
  __shared__ int   token_s;

  if (tid == 0) {
    int tok;
    if (tf_flag[0]) tok = captions[b * T_ + (t > 0 ? t - 1 : 0)];
    else if (t == 0) tok = captions[b * T_];
    else tok = (int)(0xFFFFFFFFu - (unsigned)(argkey[b] & 0xFFFFFFFFull));
    token_s = tok;
    argkey[b] = 0ull;
  }

  float p = h_cur[b * H_ + tid]       * Wa[tid]
          + h_cur[b * H_ + tid + 256] * Wa[tid + 256]
          + c_cur[b * H_ + tid]       * Wa[512 + tid]
          + c_cur[b * H_ + tid + 256] * Wa[512 + tid + 256];
  for (int o = 32; o; o >>= 1) p += __shfl_down(p, o);
  if ((tid & 63) == 0) sred[tid >> 6] = p;
  __syncthreads();

  if (tid < K_) {
    float ss = sred[0] + sred[1] + sred[2] + sred[3] + ba[0];
    float s = tanhf(ss + enc_score[b * K_ + tid]);
    float m = s;
    for (int o = 32; o; o >>= 1) m = fmaxf(m, __shfl_xor(m, o));
    float e = expf(s - m);
    float sum = e;
    for (int o = 32; o; o >>= 1) sum += __shfl_xor(sum, o);
    attn_s[tid] = e / sum;
  }
  __syncthreads();

  const float* encb = enc + (size_t)b * K_ * E_;
  for (int e = tid; e < E_; e += 256) {
    float acc = 0.f;
    #pragma unroll 8
    for (int k = 0; k < K_; ++k) acc += attn_s[k] * encb[(size_t)k * E_ + e];
    finalb[b * KIN + 2 * H_ + e] = f2bf_rne(acc);
  }
  int tok = token_s;
  for (int m = tid; m < M_; m += 256) {
    finalb[b * KIN + 2 * H_ + E_ + m] = f2bf_rne(embt[(size_t)tok * M_ + m]);
  }
}

// ---- per step: logits = final_input @ Wl^T + bl  -------------------------
// Per-wave async pipeline: each wave streams its own 16 Wl rows via
// global_load_lds into a 6-slot LDS ring (counted vmcnt(4), no barriers in
// the K-loop). A (finalb, 128KB) staged once per block via DMA, XOR-swizzled
// through the pre-swizzled-global-source trick (rule #21).
#define WAITV(n) asm volatile("s_waitcnt vmcnt(" #n ")" ::: "memory")

__global__ __launch_bounds__(256) void k_logits(
    const unsigned short* __restrict__ wl_bf,
    const unsigned short* __restrict__ finalb, const float* __restrict__ bl,
    const int* __restrict__ tf_flag, unsigned long long* __restrict__ argkey,
    float* __restrict__ out, int t) {
  extern __shared__ unsigned char lds[];
  unsigned char* Alds = lds;                       // [32 rows][256 slots *16B] = 128KB
  int tid = threadIdx.x;
  int l  = tid & 63;
  int w  = tid >> 6;
  int lv = l & 15;
  int lg = l >> 4;
  int v  = blockIdx.x * 64 + w * 16 + lv;
  unsigned char* Bw = lds + 131072 + w * 6144;     // 6 slots * 1024B per wave

  // ---- stage A: 32 DMA instrs per wave; slot swizzle phys = slot^(row&15)
  #pragma unroll
  for (int q = 0; q < 32; ++q) {
    int i = w * 32 + q;                 // instr id 0..127, 1KB each
    int row = i >> 2;                   // 4 instrs per 4KB row
    int phys = ((i & 3) << 6) + l;      // 16B-slot within row, 0..255
    int gslot = phys ^ (row & 15);
    gload16(finalb + row * 2048 + gslot * 8, Alds + i * 1024);
  }
  __syncthreads();                      // drains vmcnt(0) + barrier: A ready

  // ---- B stream setup: lane's source row/sub (pre-swizzled global source)
  int rowB = blockIdx.x * 64 + w * 16 + (l >> 2);
  int sub2 = (l & 3) ^ ((l >> 3) & 3);  // inverse of read swizzle sub^((row>>1)&3)
  const unsigned short* gB = wl_bf + (size_t)rowB * 2048 + sub2 * 8;
  #pragma unroll
  for (int p = 0; p < 5; ++p) gload16(gB + p * 32, Bw + p * 1024);

  int bro = lv * 64 + ((lg ^ ((lv >> 1) & 3)) << 4);  // swizzled B read offset

  f32x4 acc0 = {0.f, 0.f, 0.f, 0.f};
  f32x4 acc1 = {0.f, 0.f, 0.f, 0.f};

#define LSLICE(kk, W, DOISS) do {                                              \
    WAITV(W);                                                                  \
    bf16x8 bfr = *(const bf16x8*)(Bw + ((kk) % 6) * 1024 + bro);               \
    int ao_ = ((((kk) * 4) + lg) ^ lv) << 4;                                   \
    bf16x8 a0 = *(const bf16x8*)(Alds + lv * 4096 + ao_);                      \
    bf16x8 a1 = *(const bf16x8*)(Alds + (16 + lv) * 4096 + ao_);               \
    if (DOISS) gload16(gB + ((kk) + 5) * 32, Bw + (((kk) + 5) % 6) * 1024);    \
    acc0 = __builtin_amdgcn_mfma_f32_16x16x32_bf16(a0, bfr, acc0, 0, 0, 0);    \
    acc1 = __builtin_amdgcn_mfma_f32_16x16x32_bf16(a1, bfr, acc1, 0, 0, 0);    \
  } while (0)

  for (int kk = 0; kk < 59; ++kk) LSLICE(kk, 4, true);
  LSLICE(59, 4, false);
  LSLICE(60, 3, false);
  LSLICE(61, 2, false);
  LSLICE(62, 1, false);
  LSLICE(63, 0, false);
#undef LSLICE

  float blv = bl[v];
  int r0 = lg * 4;
  bool do_arg = (tf_flag[0] == 0);
  #pragma unroll
  for (int j = 0; j < 4; ++j) {
    float x0 = acc0[j] + blv;
    float x1 = acc1[j] + blv;
    out[(size_t)(r0 + j) * (T_ * V_) + (size_t)t * V_ + v] = x0;
    out[(size_t)(16 + r0 + j) * (T_ * V_) + (size_t)t * V_ + v] = x1;
    if (do_arg) {
      unsigned long long k0 = ((unsigned long long)ordf(x0) << 32) | (0xFFFFFFFFu - (unsigned)v);
      unsigned long long k1 = ((unsigned long long)ordf(x1) << 32) | (0xFFFFFFFFu - (unsigned)v);
      atomicMax(&argkey[r0 + j], k0);
      atomicMax(&argkey[16 + r0 + j], k1);
    }
  }
}

// ---- per step: LSTM via MFMA (weights read once), fused gate update ------
__global__ __launch_bounds__(256) void k_lstm(
    const unsigned short* __restrict__ whi, const unsigned short* __restrict__ wlo,
    const unsigned short* __restrict__ finalb_cur,
    const float* __restrict__ b_ih, const float* __restrict__ b_hh,
    const float* __restrict__ c_cur,
    float* __restrict__ h_nxt, float* __restrict__ c_nxt,
    unsigned short* __restrict__ finalb_nxt) {
  int tid = threadIdx.x;
  int g   = tid >> 6;
  int l   = tid & 63;
  int lv  = l & 15;
  int lg  = l >> 4;
  int ii0 = blockIdx.x * 16;

  __shared__ float gs[4][16][32];

  int j = g * H_ + ii0 + lv;
  const unsigned short* ahi = whi + (size_t)j * KL + lg * 8;
  const unsigned short* alo = wlo + (size_t)j * KL + lg * 8;
  const unsigned short* b0r = finalb_cur + lv * KIN;
  const unsigned short* b1r = finalb_cur + (16 + lv) * KIN;

  f32x4 acc0 = {0.f, 0.f, 0.f, 0.f};
  f32x4 acc1 = {0.f, 0.f, 0.f, 0.f};

  #pragma unroll 8
  for (int kk = 0; kk < KL / 32; ++kk) {
    int kb = kk * 32;
    int koff = kb + lg * 8;
    int boff = (kb < E_ + M_) ? (2 * H_ + koff) : (koff - (E_ + M_));
    bf16x8 a_hi = *(const bf16x8*)(ahi + kb);
    bf16x8 a_lo = *(const bf16x8*)(alo + kb);
    bf16x8 bb0  = *(const bf16x8*)(b0r + boff);
    bf16x8 bb1  = *(const bf16x8*)(b1r + boff);
    acc0 = __builtin_amdgcn_mfma_f32_16x16x32_bf16(a_hi, bb0, acc0, 0, 0, 0);
    acc0 = __builtin_amdgcn_mfma_f32_16x16x32_bf16(a_lo, bb0, acc0, 0, 0, 0);
    acc1 = __builtin_amdgcn_mfma_f32_16x16x32_bf16(a_hi, bb1, acc1, 0, 0, 0);
    acc1 = __builtin_amdgcn_mfma_f32_16x16x32_bf16(a_lo, bb1, acc1, 0, 0, 0);
  }

  #pragma unroll
  for (int jreg = 0; jreg < 4; ++jreg) {
    gs[g][4 * lg + jreg][lv]      = acc0[jreg];
    gs[g][4 * lg + jreg][16 + lv] = acc1[jreg];
  }
  __syncthreads();

  #pragma unroll
  for (int r = 0; r < 2; ++r) {
    int idx = tid + r * 256;
    int b  = idx & 31;
    int ii = idx >> 5;
    int iglob = ii0 + ii;
    float ig = gs[0][ii][b] + b_ih[0 * H_ + iglob] + b_hh[0 * H_ + iglob];
    float fg = gs[1][ii][b] + b_ih[1 * H_ + iglob] + b_hh[1 * H_ + iglob];
    float gg = gs[2][ii][b] + b_ih[2 * H_ + iglob] + b_hh[2 * H_ + iglob];
    float og = gs[3][ii][b] + b_ih[3 * H_ + iglob] + b_hh[3 * H_ + iglob];
    float cv = c_cur[b * H_ + iglob];
    float cn = sigm(fg) * cv + sigm(ig) * tanhf(gg);
    float hn = sigm(og) * tanhf(cn);
    c_nxt[b * H_ + iglob] = cn;
    h_nxt[b * H_ + iglob] = hn;
    finalb_nxt[b * KIN + iglob]      = f2bf_rne(hn);
    finalb_nxt[b * KIN + H_ + iglob] = f2bf_rne(cn);
  }
}

// ---- final: in-place log_softmax, online max+sum (2 passes) --------------
__global__ void k_lsm(float* __restrict__ out) {
  float4* p = (float4*)(out + (size_t)blockIdx.x * V_);
  int tid = threadIdx.x;
  __shared__ float smax[4], ssum[4];
  const int N4 = V_ / 4;
  float m = -1e30f, s = 0.f;
  for (int i = tid; i < N4; i += 256) {
    float4 v = p[i];
    float lm = fmaxf(fmaxf(v.x, v.y), fmaxf(v.z, v.w));
    if (lm > m) { s *= expf(m - lm); m = lm; }
    s += expf(v.x - m) + expf(v.y - m) + expf(v.z - m) + expf(v.w - m);
  }
  for (int o = 32; o; o >>= 1) {
    float m2 = __shfl_xor(m, o), s2 = __shfl_xor(s, o);
    float mn = fmaxf(m, m2);
    s = s * expf(m - mn) + s2 * expf(m2 - mn);
    m = mn;
  }
  if ((tid & 63) == 0) { smax[tid >> 6] = m; ssum[tid >> 6] = s; }
  __syncthreads();
  float mg = fmaxf(fmaxf(smax[0], smax[1]), fmaxf(smax[2], smax[3]));
  float sg = ssum[0] * expf(smax[0] - mg) + ssum[1] * expf(smax[1] - mg)
           + ssum[2] * expf(smax[2] - mg) + ssum[3] * expf(smax[3] - mg);
  float lse = mg + logf(sg);
  for (int i = tid; i < N4; i += 256) {
    float4 v = p[i];
    v.x -= lse; v.y -= lse; v.z -= lse; v.w -= lse;
    p[i] = v;
  }
}

extern "C" void kernel_launch(void* const* d_in, const int* in_sizes, int n_in,
                              void* d_out, int out_size, void* d_ws, size_t ws_size,
                              hipStream_t stream) {
  const float* enc      = (const float*)d_in[0];
  const float* embt     = (const float*)d_in[1];
  const float* Wa       = (const float*)d_in[2];
  const float* ba       = (const float*)d_in[3];
  const float* W_ih     = (const float*)d_in[4];
  const float* W_hh     = (const float*)d_in[5];
  const float* b_ih     = (const float*)d_in[6];
  const float* b_hh     = (const float*)d_in[7];
  const float* Wl       = (const float*)d_in[8];
  const float* bl       = (const float*)d_in[9];
  const int*   captions = (const int*)d_in[10];
  const int*   tf       = (const int*)d_in[11];
  float* out = (float*)d_out;
  char*  ws  = (char*)d_ws;

  size_t off = 0;
  unsigned short* finalb2 = (unsigned short*)(ws + off); off += (size_t)2 * B_ * KIN * 2;
  float* hb               = (float*)(ws + off);          off += (size_t)2 * B_ * H_ * 4;
  float* cb               = (float*)(ws + off);          off += (size_t)2 * B_ * H_ * 4;
  float* enc_score        = (float*)(ws + off);          off += (size_t)B_ * K_ * 4;
  unsigned long long* argkey = (unsigned long long*)(ws + off); off += 256;
  off = (off + 1023) & ~(size_t)1023;
  unsigned short* whi = (unsigned short*)(ws + off); off += (size_t)4 * H_ * KL * 2;
  unsigned short* wlo = (unsigned short*)(ws + off); off += (size_t)4 * H_ * KL * 2;
  unsigned short* wl_bf = (unsigned short*)(ws + off); off += (size_t)V_ * KIN * 2;

  unsigned short* finalb[2] = { finalb2, finalb2 + B_ * KIN };
  float* hbuf[2] = { hb, hb + B_ * H_ };
  float* cbuf[2] = { cb, cb + B_ * H_ };

  k_init<<<64, 256, 0, stream>>>(enc, Wa, hbuf[0], cbuf[0], finalb[0], enc_score);
  k_conv<<<8192, 256, 0, stream>>>(Wl, wl_bf, V_ * KIN / 4);
  k_convW<<<4 * H_ * KL / 1024, 256, 0, stream>>>(W_ih, W_hh, whi, wlo);

  const int LOGITS_LDS = 131072 + 4 * 6144;   // A 128KB + 4 waves * 6KB ring

  for (int t = 0; t < T_; ++t) {
    int cur = t & 1, nxt = cur ^ 1;
    k_attn<<<B_, 256, 0, stream>>>(enc, embt, Wa, ba, captions, tf,
                                   hbuf[cur], cbuf[cur], enc_score, argkey,
                                   finalb[cur], t);
    k_logits<<<V_ / 64, 256, LOGITS_LDS, stream>>>(wl_bf, finalb[cur], bl, tf,
                                                   argkey, out, t);
    k_lstm<<<H_ / 16, 256, 0, stream>>>(whi, wlo, finalb[cur], b_ih, b_hh,
                                        cbuf[cur], hbuf[nxt], cbuf[nxt], finalb[nxt]);
  }
  k_lsm<<<B_ * T_, 256, 0, stream>>>(out);
}

// Round 5
// 963.957 us; speedup vs baseline: 2.2938x; 1.3265x over previous
//
#include <hip/hip_runtime.h>
#include <hip/hip_bf16.h>
#include <stdint.h>

#define B_   32
#define K_   64
#define E_   512
#define H_   512
#define M_   512
#define T_   20
#define V_   32000
#define KIN  2048   // 2H + E + M
#define KL   1536   // E + M + H (lstm concat K)

typedef __bf16 bf16x8 __attribute__((ext_vector_type(8)));
typedef float  f32x4  __attribute__((ext_vector_type(4)));

__device__ inline unsigned short f2bf_rne(float f) {
  union { float f; unsigned u; } v; v.f = f;
  unsigned r = v.u + 0x7FFFu + ((v.u >> 16) & 1u);
  return (unsigned short)(r >> 16);
}
__device__ inline float bf2f(unsigned short s) {
  union { unsigned u; float f; } v; v.u = ((unsigned)s) << 16;
  return v.f;
}
__device__ inline float sigm(float x) { return 1.f / (1.f + expf(-x)); }
__device__ inline unsigned ordf(float f) {
  unsigned u = __float_as_uint(f);
  return (u & 0x80000000u) ? ~u : (u | 0x80000000u);
}

__device__ __forceinline__ void gload16(const void* g, void* l) {
  __builtin_amdgcn_global_load_lds(
      (const __attribute__((address_space(1))) void*)g,
      (__attribute__((address_space(3))) void*)l, 16, 0, 0);
}

// ---- once: Wl fp32 -> bf16 (NT loads: don't pollute L3 with fp32) --------
__global__ void k_conv(const float* __restrict__ src, unsigned short* __restrict__ dst, int n4) {
  int i = blockIdx.x * blockDim.x + threadIdx.x;
  int stride = gridDim.x * blockDim.x;
  for (; i < n4; i += stride) {
    f32x4 v = __builtin_nontemporal_load((const f32x4*)src + i);
    ushort4 o;
    o.x = f2bf_rne(v.x); o.y = f2bf_rne(v.y); o.z = f2bf_rne(v.z); o.w = f2bf_rne(v.w);
    ((ushort4*)dst)[i] = o;
  }
}

// ---- once: [W_ih | W_hh] -> bf16 hi/lo split ([2048][1536]) --------------
__global__ void k_convW(const float* __restrict__ W_ih, const float* __restrict__ W_hh,
                        unsigned short* __restrict__ whi, unsigned short* __restrict__ wlo) {
  int idx4 = blockIdx.x * 256 + threadIdx.x;
  int j  = idx4 / (KL / 4);
  int k0 = (idx4 % (KL / 4)) * 4;
  float4 w;
  if (k0 < E_ + M_) w = *(const float4*)(W_ih + (size_t)j * (E_ + M_) + k0);
  else              w = *(const float4*)(W_hh + (size_t)j * H_ + (k0 - (E_ + M_)));
  ushort4 hi, lo;
  float f[4] = {w.x, w.y, w.z, w.w};
  unsigned short hs[4], ls[4];
  #pragma unroll
  for (int q = 0; q < 4; ++q) {
    hs[q] = f2bf_rne(f[q]);
    ls[q] = f2bf_rne(f[q] - bf2f(hs[q]));
  }
  hi.x = hs[0]; hi.y = hs[1]; hi.z = hs[2]; hi.w = hs[3];
  lo.x = ls[0]; lo.y = ls[1]; lo.z = ls[2]; lo.w = ls[3];
  *(ushort4*)(whi + (size_t)j * KL + k0) = hi;
  *(ushort4*)(wlo + (size_t)j * KL + k0) = lo;
}

// ---- once: h0=c0=enc[:,-1,:] (fp32 + bf16 into finalb[0]), enc_score ----
__global__ void k_init(const float* __restrict__ enc, const float* __restrict__ Wa,
                       float* __restrict__ h0, float* __restrict__ c0,
                       unsigned short* __restrict__ finalb0,
                       float* __restrict__ enc_score) {
  int idx = blockIdx.x * 256 + threadIdx.x;
  int b = idx >> 9, i = idx & 511;
  float v = enc[(size_t)b * K_ * E_ + (size_t)(K_ - 1) * E_ + i];
  h0[b * H_ + i] = v;
  c0[b * H_ + i] = v;
  unsigned short bv = f2bf_rne(v);
  finalb0[b * KIN + i] = bv;
  finalb0[b * KIN + H_ + i] = bv;
  if (idx < B_ * K_) {
    int bb = idx >> 6, k = idx & 63;
    const float4* e4  = (const float4*)(enc + ((size_t)bb * K_ + k) * E_);
    const float4* wa4 = (const float4*)(Wa + 2 * H_);
    float acc = 0.f;
    #pragma unroll 4
    for (int q = 0; q < E_ / 4; ++q) {
      float4 a = e4[q], w = wa4[q];
      acc += a.x * w.x + a.y * w.y + a.z * w.z + a.w * w.w;
    }
    enc_score[idx] = acc;
  }
}

// ---- per step: attention + context + emb -> finalb[cur][1024:2048] -------
__global__ void k_attn(const float* __restrict__ enc, const float* __restrict__ embt,
                       const float* __restrict__ Wa, const float* __restrict__ ba,
                       const int* __restrict__ captions, const int* __restrict__ tf_flag,
                       const float* __restrict__ h_cur, const float* __restrict__ c_cur,
                       const float* __restrict__ enc_score,
                       unsigned long long* __restrict__ argkey,
                       unsigned short* __restrict__ finalb, int t) {
  int b = blockIdx.x;
  int tid = threadIdx.x;
  __shared__ float sred[4];
  __shared__ float attn_s[K_];
  __shared__ int   token_s;

  if (tid == 0) {
    int tok;
    if (tf_flag[0]) tok = captions[b * T_ + (t > 0 ? t - 1 : 0)];
    else if (t == 0) tok = captions[b * T_];
    else tok = (int)(0xFFFFFFFFu - (unsigned)(argkey[b] & 0xFFFFFFFFull));
    token_s = tok;
    argkey[b] = 0ull;
  }

  float p = h_cur[b * H_ + tid]       * Wa[tid]
          + h_cur[b * H_ + tid + 256] * Wa[tid + 256]
          + c_cur[b * H_ + tid]       * Wa[512 + tid]
          + c_cur[b * H_ + tid + 256] * Wa[512 + tid + 256];
  for (int o = 32; o; o >>= 1) p += __shfl_down(p, o);
  if ((tid & 63) == 0) sred[tid >> 6] = p;
  __syncthreads();

  if (tid < K_) {
    float ss = sred[0] + sred[1] + sred[2] + sred[3] + ba[0];
    float s = tanhf(ss + enc_score[b * K_ + tid]);
    float m = s;
    for (int o = 32; o; o >>= 1) m = fmaxf(m, __shfl_xor(m, o));
    float e = expf(s - m);
    float sum = e;
    for (int o = 32; o; o >>= 1) sum += __shfl_xor(sum, o);
    attn_s[tid] = e / sum;
  }
  __syncthreads();

  if (tid < 128) {
    // context: float4 over e, all 64 k
    const float4* enc4 = (const float4*)(enc + (size_t)b * K_ * E_);
    float4 acc = {0.f, 0.f, 0.f, 0.f};
    #pragma unroll 8
    for (int k = 0; k < K_; ++k) {
      float a = attn_s[k];
      float4 e = enc4[k * (E_ / 4) + tid];
      acc.x += a * e.x; acc.y += a * e.y; acc.z += a * e.z; acc.w += a * e.w;
    }
    ushort4 o;
    o.x = f2bf_rne(acc.x); o.y = f2bf_rne(acc.y);
    o.z = f2bf_rne(acc.z); o.w = f2bf_rne(acc.w);
    *(ushort4*)(finalb + b * KIN + 2 * H_ + tid * 4) = o;
  } else {
    int m4 = tid - 128;   // 0..127
    float4 e = *(const float4*)(embt + (size_t)token_s * M_ + m4 * 4);
    ushort4 o;
    o.x = f2bf_rne(e.x); o.y = f2bf_rne(e.y);
    o.z = f2bf_rne(e.z); o.w = f2bf_rne(e.w);
    *(ushort4*)(finalb + b * KIN + 2 * H_ + E_ + m4 * 4) = o;
  }
}

// ---- per step: FUSED logits (all blocks) + LSTM (blocks 0-31) ------------
// 250 blocks x 512 threads, 1 block/CU (single round). A (finalb, 128KB)
// staged to LDS via DMA with XOR slot swizzle; B (Wl rows) loaded straight
// global->VGPR (per-lane frag addresses are 64B-coalesced per row), compiler
// software-pipelines (no barriers in the loop). Blocks 0-31 then run one
// 16-row LSTM chunk, K split across the 8 waves, B-operand read from A-LDS.
__global__ __launch_bounds__(512) void k_logits_lstm(
    const unsigned short* __restrict__ wl_bf,
    const unsigned short* __restrict__ finalb, const float* __restrict__ bl,
    const int* __restrict__ tf_flag, unsigned long long* __restrict__ argkey,
    float* __restrict__ out, int t,
    const unsigned short* __restrict__ whi, const unsigned short* __restrict__ wlo,
    const float* __restrict__ b_ih, const float* __restrict__ b_hh,
    const float* __restrict__ c_cur, float* __restrict__ h_nxt,
    float* __restrict__ c_nxt, unsigned short* __restrict__ finalb_nxt) {
  extern __shared__ unsigned char lds[];
  unsigned char* Alds = lds;                      // 128KB: [32 rows][256 16B-slots]
  int tid = threadIdx.x;
  int l  = tid & 63;
  int w  = tid >> 6;        // 0..7
  int lv = l & 15;
  int lg = l >> 4;
  int blk = blockIdx.x;
  int v  = blk * 128 + w * 16 + lv;

  // stage A: 16 DMA instrs per lane; LDS slot s holds global slot s^(row&15)
  #pragma unroll
  for (int q = 0; q < 16; ++q) {
    int i = w * 16 + q;                 // 0..127, 1KB each
    int row = i >> 2;
    int phys = ((i & 3) << 6) + l;
    int gslot = phys ^ (row & 15);
    gload16(finalb + row * 2048 + gslot * 8, Alds + i * 1024);
  }
  __syncthreads();

  const unsigned short* gB = wl_bf + (size_t)v * 2048 + lg * 8;
  f32x4 acc0 = {0.f, 0.f, 0.f, 0.f};
  f32x4 acc1 = {0.f, 0.f, 0.f, 0.f};

  #pragma unroll 16
  for (int kk = 0; kk < 64; ++kk) {
    bf16x8 bfr = *(const bf16x8*)(gB + kk * 32);
    int ao_ = (((kk * 4) + lg) ^ lv) << 4;
    bf16x8 a0 = *(const bf16x8*)(Alds + lv * 4096 + ao_);
    bf16x8 a1 = *(const bf16x8*)(Alds + (16 + lv) * 4096 + ao_);
    acc0 = __builtin_amdgcn_mfma_f32_16x16x32_bf16(a0, bfr, acc0, 0, 0, 0);
    acc1 = __builtin_amdgcn_mfma_f32_16x16x32_bf16(a1, bfr, acc1, 0, 0, 0);
  }

  float blv = bl[v];
  int r0 = lg * 4;
  bool do_arg = (tf_flag[0] == 0);
  #pragma unroll
  for (int j = 0; j < 4; ++j) {
    float x0 = acc0[j] + blv;
    float x1 = acc1[j] + blv;
    out[(size_t)(r0 + j) * (T_ * V_) + (size_t)t * V_ + v] = x0;
    out[(size_t)(16 + r0 + j) * (T_ * V_) + (size_t)t * V_ + v] = x1;
    if (do_arg) {
      unsigned long long k0 = ((unsigned long long)ordf(x0) << 32) | (0xFFFFFFFFu - (unsigned)v);
      unsigned long long k1 = ((unsigned long long)ordf(x1) << 32) | (0xFFFFFFFFu - (unsigned)v);
      atomicMax(&argkey[r0 + j], k0);
      atomicMax(&argkey[16 + r0 + j], k1);
    }
  }

  // ---- LSTM chunk (blocks 0-31): rows ii0..ii0+16, K split over 8 waves --
  if (blk < B_) {
    __syncthreads();                    // A-LDS reads below; logits done
    float* gs2 = (float*)(lds + 131072);   // [2][4][16][32] = 16KB
    int g  = w & 3;                     // gate
    int h2 = w >> 2;                    // K-half
    int ii0 = blk * 16;
    int j = g * H_ + ii0 + lv;
    const unsigned short* ahi = whi + (size_t)j * KL + h2 * 768 + lg * 8;
    const unsigned short* alo = wlo + (size_t)j * KL + h2 * 768 + lg * 8;

    f32x4 ac0 = {0.f, 0.f, 0.f, 0.f};
    f32x4 ac1 = {0.f, 0.f, 0.f, 0.f};
    #pragma unroll 8
    for (int kk = 0; kk < 24; ++kk) {
      int k0 = h2 * 768 + kk * 32;                      // lstm-k of this slice
      int boff0 = (k0 < E_ + M_) ? (2 * H_ + k0) : (k0 - (E_ + M_));
      int s0 = (boff0 >> 3) + lg;                       // global 16B slot
      bf16x8 a_hi = *(const bf16x8*)(ahi + kk * 32);
      bf16x8 a_lo = *(const bf16x8*)(alo + kk * 32);
      bf16x8 bb0  = *(const bf16x8*)(Alds + lv * 4096 + ((s0 ^ lv) << 4));
      bf16x8 bb1  = *(const bf16x8*)(Alds + (16 + lv) * 4096 + ((s0 ^ lv) << 4));
      ac0 = __builtin_amdgcn_mfma_f32_16x16x32_bf16(a_hi, bb0, ac0, 0, 0, 0);
      ac0 = __builtin_amdgcn_mfma_f32_16x16x32_bf16(a_lo, bb0, ac0, 0, 0, 0);
      ac1 = __builtin_amdgcn_mfma_f32_16x16x32_bf16(a_hi, bb1, ac1, 0, 0, 0);
      ac1 = __builtin_amdgcn_mfma_f32_16x16x32_bf16(a_lo, bb1, ac1, 0, 0, 0);
    }
    #pragma unroll
    for (int jr = 0; jr < 4; ++jr) {
      gs2[((h2 * 4 + g) * 16 + 4 * lg + jr) * 32 + lv]      = ac0[jr];
      gs2[((h2 * 4 + g) * 16 + 4 * lg + jr) * 32 + 16 + lv] = ac1[jr];
    }
    __syncthreads();

    {
      int b  = tid & 31;
      int ii = tid >> 5;               // 0..15
      int iglob = ii0 + ii;
      float ig = gs2[((0) * 16 + ii) * 32 + b] + gs2[((4) * 16 + ii) * 32 + b]
               + b_ih[0 * H_ + iglob] + b_hh[0 * H_ + iglob];
      float fg = gs2[((1) * 16 + ii) * 32 + b] + gs2[((5) * 16 + ii) * 32 + b]
               + b_ih[1 * H_ + iglob] + b_hh[1 * H_ + iglob];
      float gg = gs2[((2) * 16 + ii) * 32 + b] + gs2[((6) * 16 + ii) * 32 + b]
               + b_ih[2 * H_ + iglob] + b_hh[2 * H_ + iglob];
      float og = gs2[((3) * 16 + ii) * 32 + b] + gs2[((7) * 16 + ii) * 32 + b]
               + b_ih[3 * H_ + iglob] + b_hh[3 * H_ + iglob];
      float cv = c_cur[b * H_ + iglob];
      float cn = sigm(fg) * cv + sigm(ig) * tanhf(gg);
      float hn = sigm(og) * tanhf(cn);
      c_nxt[b * H_ + iglob] = cn;
      h_nxt[b * H_ + iglob] = hn;
      finalb_nxt[b * KIN + iglob]      = f2bf_rne(hn);
      finalb_nxt[b * KIN + H_ + iglob] = f2bf_rne(cn);
    }
  }
}

// ---- final: in-place log_softmax, online max+sum (2 passes) --------------
__global__ void k_lsm(float* __restrict__ out) {
  float4* p = (float4*)(out + (size_t)blockIdx.x * V_);
  int tid = threadIdx.x;
  __shared__ float smax[4], ssum[4];
  const int N4 = V_ / 4;
  float m = -1e30f, s = 0.f;
  for (int i = tid; i < N4; i += 256) {
    float4 v = p[i];
    float lm = fmaxf(fmaxf(v.x, v.y), fmaxf(v.z, v.w));
    if (lm > m) { s *= expf(m - lm); m = lm; }
    s += expf(v.x - m) + expf(v.y - m) + expf(v.z - m) + expf(v.w - m);
  }
  for (int o = 32; o; o >>= 1) {
    float m2 = __shfl_xor(m, o), s2 = __shfl_xor(s, o);
    float mn = fmaxf(m, m2);
    s = s * expf(m - mn) + s2 * expf(m2 - mn);
    m = mn;
  }
  if ((tid & 63) == 0) { smax[tid >> 6] = m; ssum[tid >> 6] = s; }
  __syncthreads();
  float mg = fmaxf(fmaxf(smax[0], smax[1]), fmaxf(smax[2], smax[3]));
  float sg = ssum[0] * expf(smax[0] - mg) + ssum[1] * expf(smax[1] - mg)
           + ssum[2] * expf(smax[2] - mg) + ssum[3] * expf(smax[3] - mg);
  float lse = mg + logf(sg);
  for (int i = tid; i < N4; i += 256) {
    float4 v = p[i];
    v.x -= lse; v.y -= lse; v.z -= lse; v.w -= lse;
    p[i] = v;
  }
}

extern "C" void kernel_launch(void* const* d_in, const int* in_sizes, int n_in,
                              void* d_out, int out_size, void* d_ws, size_t ws_size,
                              hipStream_t stream) {
  const float* enc      = (const float*)d_in[0];
  const float* embt     = (const float*)d_in[1];
  const float* Wa       = (const float*)d_in[2];
  const float* ba       = (const float*)d_in[3];
  const float* W_ih     = (const float*)d_in[4];
  const float* W_hh     = (const float*)d_in[5];
  const float* b_ih     = (const float*)d_in[6];
  const float* b_hh     = (const float*)d_in[7];
  const float* Wl       = (const float*)d_in[8];
  const float* bl       = (const float*)d_in[9];
  const int*   captions = (const int*)d_in[10];
  const int*   tf       = (const int*)d_in[11];
  float* out = (float*)d_out;
  char*  ws  = (char*)d_ws;

  size_t off = 0;
  unsigned short* finalb2 = (unsigned short*)(ws + off); off += (size_t)2 * B_ * KIN * 2;
  float* hb               = (float*)(ws + off);          off += (size_t)2 * B_ * H_ * 4;
  float* cb               = (float*)(ws + off);          off += (size_t)2 * B_ * H_ * 4;
  float* enc_score        = (float*)(ws + off);          off += (size_t)B_ * K_ * 4;
  unsigned long long* argkey = (unsigned long long*)(ws + off); off += 256;
  off = (off + 1023) & ~(size_t)1023;
  unsigned short* whi = (unsigned short*)(ws + off); off += (size_t)4 * H_ * KL * 2;
  unsigned short* wlo = (unsigned short*)(ws + off); off += (size_t)4 * H_ * KL * 2;
  unsigned short* wl_bf = (unsigned short*)(ws + off); off += (size_t)V_ * KIN * 2;

  unsigned short* finalb[2] = { finalb2, finalb2 + B_ * KIN };
  float* hbuf[2] = { hb, hb + B_ * H_ };
  float* cbuf[2] = { cb, cb + B_ * H_ };

  k_init<<<64, 256, 0, stream>>>(enc, Wa, hbuf[0], cbuf[0], finalb[0], enc_score);
  k_conv<<<8192, 256, 0, stream>>>(Wl, wl_bf, V_ * KIN / 4);
  k_convW<<<4 * H_ * KL / 1024, 256, 0, stream>>>(W_ih, W_hh, whi, wlo);

  const int FUSED_LDS = 131072 + 16384;   // A 128KB + gs2 16KB

  for (int t = 0; t < T_; ++t) {
    int cur = t & 1, nxt = cur ^ 1;
    k_attn<<<B_, 256, 0, stream>>>(enc, embt, Wa, ba, captions, tf,
                                   hbuf[cur], cbuf[cur], enc_score, argkey,
                                   finalb[cur], t);
    k_logits_lstm<<<V_ / 128, 512, FUSED_LDS, stream>>>(
        wl_bf, finalb[cur], bl, tf, argkey, out, t,
        whi, wlo, b_ih, b_hh, cbuf[cur], hbuf[nxt], cbuf[nxt], finalb[nxt]);
  }
  k_lsm<<<B_ * T_, 256, 0, stream>>>(out);
}